// Round 6
// baseline (306.773 us; speedup 1.0000x reference)
//
#include <hip/hip_runtime.h>
#include <cstdint>
#include <cstddef>

#define B_ROWS 16384
#define D_DIM  1024
#define F_REAL 1034          // real hidden/feature dim
#define N_PAD  1152          // 9 * 128
#define K_PAD  1088          // 1024 h + 10 scal + 54 zero  (17 * 64)
#define NK     (K_PAD / 64)  // 17 K-tiles of BK=64 (tile 16 = scalar tail)
#define EPSN   1e-12f

typedef __bf16 bf16x8 __attribute__((ext_vector_type(8)));
typedef float  f32x4  __attribute__((ext_vector_type(4)));
typedef unsigned short u16;
typedef unsigned int   u32;

__device__ __forceinline__ u16 f2bf(float f) {
    __bf16 b = (__bf16)f;
    return __builtin_bit_cast(u16, b);
}

// pack 8 f32 (bit-carried in two uint4) -> 8 bf16 (one uint4), accumulate ssq
__device__ __forceinline__ uint4 pack8(uint4 A, uint4 B, float& ssq) {
    float f0 = __uint_as_float(A.x), f1 = __uint_as_float(A.y);
    float f2 = __uint_as_float(A.z), f3 = __uint_as_float(A.w);
    float f4 = __uint_as_float(B.x), f5 = __uint_as_float(B.y);
    float f6 = __uint_as_float(B.z), f7 = __uint_as_float(B.w);
    ssq += f0*f0 + f1*f1 + f2*f2 + f3*f3 + f4*f4 + f5*f5 + f6*f6 + f7*f7;
    uint4 w;
    w.x = (u32)f2bf(f0) | ((u32)f2bf(f1) << 16);
    w.y = (u32)f2bf(f2) | ((u32)f2bf(f3) << 16);
    w.z = (u32)f2bf(f4) | ((u32)f2bf(f5) << 16);
    w.w = (u32)f2bf(f6) | ((u32)f2bf(f7) << 16);
    return w;
}

// -------------------------------------------------------------------------
// prep R6: h REMOVED (R5 diagnosis: prep invariant at 80us across 3
// structures == path-BW ceiling ~2.4 TB/s on its 192MB of reads; only fix
// is reading less). h conversion + r_final moved into gemm. prep now reads
// only vp,vh (128MB) and writes a compact [16384][64] bf16 scalar array
// (r_final slot left 0, patched by gemm). Structure: persistent waves,
// 4 rows/wave, depth-2 row pipeline, nd/s_nn hoisted.
// -------------------------------------------------------------------------
__global__ __launch_bounds__(256)
void prep_kernel(const float* __restrict__ vp,
                 const float* __restrict__ vh, const float* __restrict__ nd,
                 const float* __restrict__ nsp, u16* __restrict__ Ascal)
{
    const int tid  = threadIdx.x;
    const int lane = tid & 63;
    const int wg   = blockIdx.x * 4 + (tid >> 6);   // 0..4095
    const int r0   = wg * 4;

    const float4* ndp = (const float4*)nd;
    float4 n[4];
    #pragma unroll
    for (int c = 0; c < 4; ++c) n[c] = ndp[lane + c * 64];
    const float ns = nsp[0];

    float s_nn = 0.f;
    #pragma unroll
    for (int c = 0; c < 4; ++c)
        s_nn += n[c].x*n[c].x + n[c].y*n[c].y + n[c].z*n[c].z + n[c].w*n[c].w;
    #pragma unroll
    for (int m = 32; m >= 1; m >>= 1) s_nn += __shfl_xor(s_nn, m, 64);
    const float nnc = fmaxf(sqrtf(s_nn), EPSN);

    float4 P[2][4], Q[2][4];

#define LOADR(st, r)                                                          \
    do {                                                                      \
        const float4* vpp = (const float4*)(vp + (size_t)(r) * D_DIM);        \
        const float4* vhp = (const float4*)(vh + (size_t)(r) * D_DIM);        \
        _Pragma("unroll")                                                     \
        for (int c = 0; c < 4; ++c) P[st][c] = vpp[lane + c * 64];            \
        _Pragma("unroll")                                                     \
        for (int c = 0; c < 4; ++c) Q[st][c] = vhp[lane + c * 64];            \
    } while (0)

    LOADR(0, r0);
    #pragma unroll
    for (int i = 0; i < 4; ++i) {
        const int st = i & 1;
        if (i + 1 < 4) LOADR(((i + 1) & 1), r0 + i + 1);
        __builtin_amdgcn_sched_barrier(0);   // keep next-row loads above use

        float s_pp = 0.f, s_hh = 0.f, s_pv = 0.f;
        float s_dd = 0.f, s_pn = 0.f, s_hn = 0.f;
        #pragma unroll
        for (int c = 0; c < 4; ++c) {
            float4 p = P[st][c], q = Q[st][c], nn = n[c];
            s_pp += p.x*p.x + p.y*p.y + p.z*p.z + p.w*p.w;
            s_hh += q.x*q.x + q.y*q.y + q.z*q.z + q.w*q.w;
            s_pv += p.x*q.x + p.y*q.y + p.z*q.z + p.w*q.w;
            float dx = q.x-p.x, dy = q.y-p.y, dz = q.z-p.z, dw = q.w-p.w;
            s_dd += dx*dx + dy*dy + dz*dz + dw*dw;
            s_pn += p.x*nn.x + p.y*nn.y + p.z*nn.z + p.w*nn.w;
            s_hn += q.x*nn.x + q.y*nn.y + q.z*nn.z + q.w*nn.w;
        }

        #pragma unroll
        for (int m = 32; m >= 1; m >>= 1) {
            s_pp += __shfl_xor(s_pp, m, 64);
            s_hh += __shfl_xor(s_hh, m, 64);
            s_pv += __shfl_xor(s_pv, m, 64);
            s_dd += __shfl_xor(s_dd, m, 64);
            s_pn += __shfl_xor(s_pn, m, 64);
            s_hn += __shfl_xor(s_hn, m, 64);
        }

        if (lane == 0) {
            float np_ = sqrtf(s_pp), nh_ = sqrtf(s_hh);
            float npc = fmaxf(np_, EPSN), nhc = fmaxf(nh_, EPSN);
            float align = s_pv / (npc * nhc);
            u16 fo[64];
            fo[0] = f2bf(align);
            fo[1] = f2bf(-align);
            fo[2] = f2bf(0.5f * (1.0f + align));      // K_O = 1
            fo[3] = f2bf(0.5f * (1.0f - align));
            fo[4] = f2bf(sqrtf(s_dd));
            fo[5] = f2bf(np_);
            fo[6] = f2bf(nh_);
            fo[7] = 0;                                // r_final patched by gemm
            fo[8] = f2bf(ns * s_pn / (npc * nnc));
            fo[9] = f2bf(ns * s_hn / (nhc * nnc));
            #pragma unroll
            for (int k = 10; k < 64; ++k) fo[k] = 0;
            u16* arow = Ascal + (size_t)(r0 + i) * 64;
            #pragma unroll
            for (int k = 0; k < 8; ++k)
                *(uint4*)(arow + k * 8) = *(uint4*)(fo + k * 8);
        }
    }
#undef LOADR
}

// -------------------------------------------------------------------------
// w1 [1034x1034] f32 -> padded bf16 B^T [1152 x 1088]; initout folded in
// (blocks < 192 also write out = b2 broadcast) -- saves one launch.
// -------------------------------------------------------------------------
__global__ __launch_bounds__(256)
void convw_kernel(const float* __restrict__ w1, u16* __restrict__ Bm,
                  const float* __restrict__ b2, float* __restrict__ out)
{
    const int i = blockIdx.x;
    for (int j = threadIdx.x; j < K_PAD; j += 256) {
        float v = (i < F_REAL && j < F_REAL) ? w1[(size_t)i * F_REAL + j] : 0.0f;
        Bm[(size_t)i * K_PAD + j] = f2bf(v);
    }
    if (i < 192) {                      // 192*256 == 16384*3
        int o = i * 256 + threadIdx.x;
        out[o] = b2[o % 3];
    }
}

// -------------------------------------------------------------------------
// GEMM1 R6: R4 structure (64x128 tile, BK=64, depth-2 register pipeline,
// zero-conflict swizzle, 2304 blocks) with A-source fusion:
//   - tiles 0..15: A staged DIRECTLY from h (f32), converted to bf16 at
//     WRITE time (same f2bf rounding as old prep); per-thread ssq of the
//     16 staged f32 accumulates toward r_final.
//   - tile 16: A staged from the 2MB Ascal array; the r_final slot
//     (chunk 0, element 7) is patched from the 4-lane shfl reduce of ssq.
//     Schedule guarantees ssq completeness: tile16 WRITE happens at kt=14,
//     after WRITE of tiles 0..15.
// Fused bias+ReLU+GEMM2 epilogue -> atomic partials (unchanged).
// -------------------------------------------------------------------------
__global__ __launch_bounds__(256)
void gemm_kernel(const float* __restrict__ hsrc,
                 const u16* __restrict__ Ascal,
                 const u16* __restrict__ Bm,
                 const float* __restrict__ b1, const float* __restrict__ w2,
                 float* __restrict__ out)
{
    // two 32-k halves; slot layout (row*4 + (kc^((row>>1)&3)))*8
    __shared__ __bf16 As[2 * 64 * 32];    // 8 KB
    __shared__ __bf16 Bs[2 * 128 * 32];   // 16 KB

    const int tid  = threadIdx.x;
    const int lane = tid & 63;
    const int wave = tid >> 6;
    const int wm = wave >> 1, wn = wave & 1;   // wave covers 32(m) x 64(n)
    const int bm = blockIdx.x, bn = blockIdx.y;

    // A staging geometry: row = tid>>2, swizzled 8-elem chunk
    const int srow = tid >> 2;
    const int achk = (tid & 3) ^ ((tid >> 3) & 3);   // zero-conflict swizzle
    const float* gaH = hsrc  + (size_t)(bm * 64 + srow) * D_DIM + achk * 8;
    const u16*   gaS = Ascal + (size_t)(bm * 64 + srow) * 64    + achk * 8;
    __bf16* lA = As + tid * 8;

    const u16* gaB[2];
    __bf16*    lB[2];
    #pragma unroll
    for (int o = 0; o < 2; ++o) {
        int s   = o * 256 + tid;
        int row = s >> 2;
        int kc  = (s & 3) ^ ((s >> 3) & 3);          // zero-conflict swizzle
        gaB[o] = Bm + (size_t)(bn * 128 + row) * K_PAD + kc * 8;
        lB[o]  = Bs + s * 8;
    }

    const int col  = lane & 15;
    const int quad = lane >> 4;
    const int swz  = quad ^ ((col >> 1) & 3);        // zero-conflict swizzle
    int aoff[2], boff[4];
    #pragma unroll
    for (int i = 0; i < 2; ++i)
        aoff[i] = ((wm * 32 + i * 16 + col) * 4 + swz) * 8;
    #pragma unroll
    for (int j = 0; j < 4; ++j)
        boff[j] = ((wn * 64 + j * 16 + col) * 4 + swz) * 8;

    f32x4 acc[2][4];
    #pragma unroll
    for (int i = 0; i < 2; ++i)
        #pragma unroll
        for (int j = 0; j < 4; ++j)
            acc[i][j] = (f32x4){0.f, 0.f, 0.f, 0.f};

    float ssq = 0.f;   // per-thread sum of squares of staged h elements

    // two register stages; tile t lives in stage t&1.
    // A regs carry f32 bits (4 uint4) for h-tiles, bf16 (a0,a1) for tile 16.
    uint4 a0_0, a1_0, a2_0, a3_0, b00_0, b01_0, b10_0, b11_0;
    uint4 a0_1, a1_1, a2_1, a3_1, b00_1, b01_1, b10_1, b11_1;

#define LOAD_STAGE(st, ko)                                                    \
    do {                                                                      \
        if ((ko) == 1024) {                                                   \
            a0_##st = *(const uint4*)(gaS);                                   \
            a1_##st = *(const uint4*)(gaS + 32);                              \
        } else {                                                              \
            a0_##st = *(const uint4*)(gaH + (ko));                            \
            a1_##st = *(const uint4*)(gaH + (ko) + 4);                        \
            a2_##st = *(const uint4*)(gaH + (ko) + 32);                       \
            a3_##st = *(const uint4*)(gaH + (ko) + 36);                       \
        }                                                                     \
        b00_##st = *(const uint4*)(gaB[0] + (ko));                            \
        b01_##st = *(const uint4*)(gaB[0] + (ko) + 32);                       \
        b10_##st = *(const uint4*)(gaB[1] + (ko));                            \
        b11_##st = *(const uint4*)(gaB[1] + (ko) + 32);                       \
    } while (0)

#define WRITE_STAGE(st, scal)                                                 \
    do {                                                                      \
        if (scal) {                                                           \
            float s_ = ssq + __shfl_xor(ssq, 1, 64);                          \
            s_ += __shfl_xor(s_, 2, 64);                                      \
            u32 rb_ = (u32)f2bf(sqrtf(s_));                                   \
            uint4 s0_ = a0_##st, s1_ = a1_##st;                               \
            if (achk == 0) s0_.w = (s0_.w & 0xFFFFu) | (rb_ << 16);           \
            *(uint4*)(lA)        = s0_;                                       \
            *(uint4*)(lA + 2048) = s1_;                                       \
        } else {                                                              \
            *(uint4*)(lA)        = pack8(a0_##st, a1_##st, ssq);              \
            *(uint4*)(lA + 2048) = pack8(a2_##st, a3_##st, ssq);              \
        }                                                                     \
        *(uint4*)(lB[0])        = b00_##st;                                   \
        *(uint4*)(lB[0] + 4096) = b01_##st;                                   \
        *(uint4*)(lB[1])        = b10_##st;                                   \
        *(uint4*)(lB[1] + 4096) = b11_##st;                                   \
    } while (0)

#define COMPUTE_TILE                                                          \
    do {                                                                      \
        _Pragma("unroll")                                                     \
        for (int h = 0; h < 2; ++h) {                                         \
            const __bf16* Ab = As + h * 2048;                                 \
            const __bf16* Bb = Bs + h * 4096;                                 \
            bf16x8 av[2], bv[4];                                              \
            _Pragma("unroll")                                                 \
            for (int i = 0; i < 2; ++i) av[i] = *(const bf16x8*)(Ab + aoff[i]); \
            _Pragma("unroll")                                                 \
            for (int j = 0; j < 4; ++j) bv[j] = *(const bf16x8*)(Bb + boff[j]); \
            _Pragma("unroll")                                                 \
            for (int i = 0; i < 2; ++i)                                       \
                _Pragma("unroll")                                             \
                for (int j = 0; j < 4; ++j)                                   \
                    acc[i][j] = __builtin_amdgcn_mfma_f32_16x16x32_bf16(      \
                                    av[i], bv[j], acc[i][j], 0, 0, 0);        \
        }                                                                     \
    } while (0)

    // prologue: t0 -> S0, t1 -> S1 (both in flight), write t0, sync
    LOAD_STAGE(0, 0);
    LOAD_STAGE(1, 64);
    WRITE_STAGE(0, false);
    __syncthreads();

    for (int kt = 0; kt < NK; kt += 2) {
        // even sub-iter kt: prefetch t(kt+2) -> S0; write t(kt+1) from S1
        if (kt + 2 < NK) LOAD_STAGE(0, (kt + 2) * 64);
        COMPUTE_TILE;
        if (kt + 1 < NK) {
            __syncthreads();
            WRITE_STAGE(1, false);              // odd tiles are never 16
            __syncthreads();

            // odd sub-iter kt+1: prefetch t(kt+3) -> S1; write t(kt+2) from S0
            if (kt + 3 < NK) LOAD_STAGE(1, (kt + 3) * 64);
            COMPUTE_TILE;
            if (kt + 2 < NK) {
                __syncthreads();
                WRITE_STAGE(0, (kt + 2) == 16); // tile 16 = scalar tail
                __syncthreads();
            }
        }
    }

    // epilogue: hidden = relu(acc + b1[n]); logits partial = hidden @ w2^T
    float bias[4], w20[4], w21[4], w22[4];
    #pragma unroll
    for (int ni = 0; ni < 4; ++ni) {
        int n = bn * 128 + wn * 64 + ni * 16 + col;
        bool v = n < F_REAL;   // padded rows have acc==0 anyway
        bias[ni] = v ? b1[n] : 0.0f;
        w20[ni]  = v ? w2[n] : 0.0f;
        w21[ni]  = v ? w2[F_REAL + n] : 0.0f;
        w22[ni]  = v ? w2[2 * F_REAL + n] : 0.0f;
    }
    #pragma unroll
    for (int mi = 0; mi < 2; ++mi) {
        float c0[4] = {0,0,0,0}, c1[4] = {0,0,0,0}, c2[4] = {0,0,0,0};
        #pragma unroll
        for (int ni = 0; ni < 4; ++ni) {
            #pragma unroll
            for (int r = 0; r < 4; ++r) {
                float hd = fmaxf(acc[mi][ni][r] + bias[ni], 0.0f);
                c0[r] += hd * w20[ni];
                c1[r] += hd * w21[ni];
                c2[r] += hd * w22[ni];
            }
        }
        #pragma unroll
        for (int m = 8; m >= 1; m >>= 1) {
            #pragma unroll
            for (int r = 0; r < 4; ++r) {
                c0[r] += __shfl_xor(c0[r], m, 64);
                c1[r] += __shfl_xor(c1[r], m, 64);
                c2[r] += __shfl_xor(c2[r], m, 64);
            }
        }
        if (col == 0) {
            int gm = bm * 64 + wm * 32 + mi * 16 + quad * 4;
            #pragma unroll
            for (int r = 0; r < 4; ++r) {
                atomicAdd(out + (size_t)(gm + r) * 3 + 0, c0[r]);
                atomicAdd(out + (size_t)(gm + r) * 3 + 1, c1[r]);
                atomicAdd(out + (size_t)(gm + r) * 3 + 2, c2[r]);
            }
        }
    }
#undef LOAD_STAGE
#undef WRITE_STAGE
#undef COMPUTE_TILE
}

extern "C" void kernel_launch(void* const* d_in, const int* in_sizes, int n_in,
                              void* d_out, int out_size, void* d_ws, size_t ws_size,
                              hipStream_t stream)
{
    const float* h  = (const float*)d_in[0];
    const float* vp = (const float*)d_in[1];
    const float* vh = (const float*)d_in[2];
    const float* nd = (const float*)d_in[3];
    const float* ns = (const float*)d_in[4];
    const float* w1 = (const float*)d_in[5];
    const float* b1 = (const float*)d_in[6];
    const float* w2 = (const float*)d_in[7];
    const float* b2 = (const float*)d_in[8];
    float* out = (float*)d_out;

    u16* Ascal = (u16*)d_ws;                              // [16384][64] bf16
    u16* Bfull = Ascal + (size_t)B_ROWS * 64;             // [1152][1088] bf16

    prep_kernel<<<1024, 256, 0, stream>>>(vp, vh, nd, ns, Ascal);
    convw_kernel<<<N_PAD, 256, 0, stream>>>(w1, Bfull, b2, out);
    gemm_kernel<<<dim3(B_ROWS / 64, N_PAD / 128), 256, 0, stream>>>(
        h, Ascal, Bfull, b1, w2, out);
}

// Round 7
// 267.689 us; speedup vs baseline: 1.1460x; 1.1460x over previous
//
#include <hip/hip_runtime.h>
#include <cstdint>
#include <cstddef>

#define B_ROWS 16384
#define D_DIM  1024
#define F_REAL 1034          // real hidden/feature dim
#define N2     1280          // padded N: 80 n-blocks of 16
#define NBLK   80
#define K2     1056          // padded K: 33 tiles of 32 (1024 h + 32 tail)
#define KT_N   33
#define EPSN   1e-12f

#define LDS_RF_OFF   65536   // u16 units: panel = 64*1024 u16 = 131072 B
#define LDS_TOTAL    134400  // 131072 (panel) + 256 (rf) + 3072 (comb)

typedef __bf16 bf16x8 __attribute__((ext_vector_type(8)));
typedef float  f32x4  __attribute__((ext_vector_type(4)));
typedef unsigned short u16;
typedef unsigned int   u32;

__device__ __forceinline__ u16 f2bf(float f) {
    __bf16 b = (__bf16)f;
    return __builtin_bit_cast(u16, b);
}

// -------------------------------------------------------------------------
// prep (R6 structure, Ascal now [16384][32]): reads ONLY vp,vh (128 MB) --
// bytes-bound at ~2.4 TB/s (structure-invariant across R0/R5/R6), ~53us.
// Writes 10 scalar features per row; slot 7 (r_final) left 0, patched by
// gemm from its own h-panel norm. Slots 10..31 zero.
// -------------------------------------------------------------------------
__global__ __launch_bounds__(256)
void prep_kernel(const float* __restrict__ vp,
                 const float* __restrict__ vh, const float* __restrict__ nd,
                 const float* __restrict__ nsp, u16* __restrict__ Ascal)
{
    const int tid  = threadIdx.x;
    const int lane = tid & 63;
    const int wg   = blockIdx.x * 4 + (tid >> 6);   // 0..4095
    const int r0   = wg * 4;

    const float4* ndp = (const float4*)nd;
    float4 n[4];
    #pragma unroll
    for (int c = 0; c < 4; ++c) n[c] = ndp[lane + c * 64];
    const float ns = nsp[0];

    float s_nn = 0.f;
    #pragma unroll
    for (int c = 0; c < 4; ++c)
        s_nn += n[c].x*n[c].x + n[c].y*n[c].y + n[c].z*n[c].z + n[c].w*n[c].w;
    #pragma unroll
    for (int m = 32; m >= 1; m >>= 1) s_nn += __shfl_xor(s_nn, m, 64);
    const float nnc = fmaxf(sqrtf(s_nn), EPSN);

    float4 P[2][4], Q[2][4];

#define LOADR(st, r)                                                          \
    do {                                                                      \
        const float4* vpp = (const float4*)(vp + (size_t)(r) * D_DIM);        \
        const float4* vhp = (const float4*)(vh + (size_t)(r) * D_DIM);        \
        _Pragma("unroll")                                                     \
        for (int c = 0; c < 4; ++c) P[st][c] = vpp[lane + c * 64];            \
        _Pragma("unroll")                                                     \
        for (int c = 0; c < 4; ++c) Q[st][c] = vhp[lane + c * 64];            \
    } while (0)

    LOADR(0, r0);
    #pragma unroll
    for (int i = 0; i < 4; ++i) {
        const int st = i & 1;
        if (i + 1 < 4) LOADR(((i + 1) & 1), r0 + i + 1);
        __builtin_amdgcn_sched_barrier(0);

        float s_pp = 0.f, s_hh = 0.f, s_pv = 0.f;
        float s_dd = 0.f, s_pn = 0.f, s_hn = 0.f;
        #pragma unroll
        for (int c = 0; c < 4; ++c) {
            float4 p = P[st][c], q = Q[st][c], nn = n[c];
            s_pp += p.x*p.x + p.y*p.y + p.z*p.z + p.w*p.w;
            s_hh += q.x*q.x + q.y*q.y + q.z*q.z + q.w*q.w;
            s_pv += p.x*q.x + p.y*q.y + p.z*q.z + p.w*q.w;
            float dx = q.x-p.x, dy = q.y-p.y, dz = q.z-p.z, dw = q.w-p.w;
            s_dd += dx*dx + dy*dy + dz*dz + dw*dw;
            s_pn += p.x*nn.x + p.y*nn.y + p.z*nn.z + p.w*nn.w;
            s_hn += q.x*nn.x + q.y*nn.y + q.z*nn.z + q.w*nn.w;
        }

        #pragma unroll
        for (int m = 32; m >= 1; m >>= 1) {
            s_pp += __shfl_xor(s_pp, m, 64);
            s_hh += __shfl_xor(s_hh, m, 64);
            s_pv += __shfl_xor(s_pv, m, 64);
            s_dd += __shfl_xor(s_dd, m, 64);
            s_pn += __shfl_xor(s_pn, m, 64);
            s_hn += __shfl_xor(s_hn, m, 64);
        }

        if (lane == 0) {
            float np_ = sqrtf(s_pp), nh_ = sqrtf(s_hh);
            float npc = fmaxf(np_, EPSN), nhc = fmaxf(nh_, EPSN);
            float align = s_pv / (npc * nhc);
            u16 fo[32];
            fo[0] = f2bf(align);
            fo[1] = f2bf(-align);
            fo[2] = f2bf(0.5f * (1.0f + align));      // K_O = 1
            fo[3] = f2bf(0.5f * (1.0f - align));
            fo[4] = f2bf(sqrtf(s_dd));
            fo[5] = f2bf(np_);
            fo[6] = f2bf(nh_);
            fo[7] = 0;                                // r_final patched by gemm
            fo[8] = f2bf(ns * s_pn / (npc * nnc));
            fo[9] = f2bf(ns * s_hn / (nhc * nnc));
            #pragma unroll
            for (int k = 10; k < 32; ++k) fo[k] = 0;
            u16* arow = Ascal + (size_t)(r0 + i) * 32;
            #pragma unroll
            for (int k = 0; k < 4; ++k)
                *(uint4*)(arow + k * 8) = *(uint4*)(fo + k * 8);
        }
    }
#undef LOADR
}

// -------------------------------------------------------------------------
// convw R7: w1 -> frag-contiguous bf16 B layout Bm2[kt][nblk][quad][col][8]
// so the gemm's bv load is 64 lanes x 16B CONTIGUOUS (1 KB) from L2.
// k-order: 0..1023 = h cols; 1024..1033 = scalar cols (w1 cols 1024..1033,
// r_final at 1031 matching Ascal slot 7); rest zero. n >= 1034 zero.
// 168960 chunks = 660 blocks x 256.
// -------------------------------------------------------------------------
__global__ __launch_bounds__(256)
void convw_kernel(const float* __restrict__ w1, u16* __restrict__ Bm2)
{
    const int o = blockIdx.x * 256 + threadIdx.x;   // chunk id, < 168960
    const int col  = o & 15;
    int t = o >> 4;
    const int quad = t & 3;
    t >>= 2;
    const int nblk = t % NBLK;
    const int kt   = t / NBLK;
    const int n = nblk * 16 + col;
    const int k = kt * 32 + quad * 8;

    u16 v[8];
    if (n < F_REAL && k + 7 < F_REAL) {
        // fast path: all kt < 32 (k+7 <= 1023) and kt==32/quad==0 partial no
        const float* src = w1 + (size_t)n * F_REAL + k;
        #pragma unroll
        for (int e = 0; e < 8; e += 2) {
            float2 f = *(const float2*)(src + e);
            v[e]   = f2bf(f.x);
            v[e+1] = f2bf(f.y);
        }
    } else {
        #pragma unroll
        for (int e = 0; e < 8; ++e) {
            float f = (n < F_REAL && k + e < F_REAL)
                        ? w1[(size_t)n * F_REAL + k + e] : 0.0f;
            v[e] = f2bf(f);
        }
    }
    *(uint4*)(Bm2 + (size_t)o * 8) = *(uint4*)v;
}

// -------------------------------------------------------------------------
// GEMM R7: panel-resident. 256 blocks (1/CU), 4 waves, dynamic LDS 134400:
//   panel[64][1024] bf16 (128 KB, chunk-XOR swizzled), rf[64], comb[768].
// Phase A: convert h panel f32->bf16 into LDS ONCE (h read once: 64 MB
//   total, kills R5's A-materialization AND R6's 9x re-read).
// Phase A2: per-row ssq from panel -> rf (r_final).
// Phase B: 5 passes of 256 cols; wave = 64m x 64n (0.5 b128/MFMA); B read
//   straight from L2 in frag-contiguous layout (no LDS staging, NO barriers
//   in the K-loop); depth-2 register pipeline over 33 K-tiles; tail tile
//   from Ascal with r_final patched into element 7 of quad 0.
// Epilogue: bias+ReLU+w2 accumulated in regs across all N; lane-reduce,
//   cross-wave LDS combine, plain stores (no atomics, no initout).
// -------------------------------------------------------------------------
__global__ __launch_bounds__(256, 1)
void gemm_kernel(const float* __restrict__ h, const u16* __restrict__ Ascal,
                 const u16* __restrict__ Bm2, const float* __restrict__ b1,
                 const float* __restrict__ w2, const float* __restrict__ b2,
                 float* __restrict__ out)
{
    extern __shared__ u16 smem[];
    u16*   panel = smem;                          // [64][1024] swizzled
    float* rf    = (float*)(smem + LDS_RF_OFF);   // 64 floats
    float* comb  = rf + 64;                       // 768 floats

    const int tid  = threadIdx.x;
    const int lane = tid & 63;
    const int wv   = tid >> 6;      // 0..3 = n-slice of 64
    const int col  = lane & 15;
    const int quad = lane >> 4;
    const int bm   = blockIdx.x;

    // ---- Phase A: h (f32, global, read once) -> bf16 LDS panel ----
    {
        const float* hblk = h + (size_t)bm * 64 * D_DIM;
        const int halfsel = tid & 1;          // 8B half within 16B chunk
        const int chunkid = tid >> 1;         // 0..127
        #pragma unroll 2
        for (int jb = 0; jb < 8; ++jb) {
            float4 v[8];
            #pragma unroll
            for (int u = 0; u < 8; ++u)
                v[u] = *(const float4*)(hblk + (size_t)(jb*8+u)*D_DIM + tid*4);
            #pragma unroll
            for (int u = 0; u < 8; ++u) {
                const int j = jb*8 + u;
                ushort4 o;
                o.x = f2bf(v[u].x); o.y = f2bf(v[u].y);
                o.z = f2bf(v[u].z); o.w = f2bf(v[u].w);
                *(ushort4*)(panel + j*1024 + ((chunkid ^ (j&7))*8) + halfsel*4) = o;
            }
        }
    }
    __syncthreads();

    // ---- Phase A2: per-row ssq (from bf16 panel, order-free) -> rf ----
    {
        const int r = wv*16 + (lane >> 2);
        const int q = lane & 3;
        float ssq = 0.f;
        #pragma unroll
        for (int c = 0; c < 32; ++c) {
            const int cc = q*32 + ((c + (lane >> 2)) & 31);  // rotate: no bank conflict
            uint4 tch = *(const uint4*)(panel + r*1024 + cc*8);
            u32 wd[4] = {tch.x, tch.y, tch.z, tch.w};
            #pragma unroll
            for (int e = 0; e < 4; ++e) {
                float lo = __uint_as_float(wd[e] << 16);
                float hi = __uint_as_float(wd[e] & 0xFFFF0000u);
                ssq += lo*lo + hi*hi;
            }
        }
        ssq += __shfl_xor(ssq, 1, 64);
        ssq += __shfl_xor(ssq, 2, 64);
        if (q == 0) rf[r] = sqrtf(ssq);
    }
    __syncthreads();

    u16 rfb[4];
    #pragma unroll
    for (int i = 0; i < 4; ++i) rfb[i] = f2bf(rf[i*16 + col]);

    const int xmask = col & 7;           // = m&7 (i*16 is 8-aligned)
    int arow[4];
    #pragma unroll
    for (int i = 0; i < 4; ++i) arow[i] = (i*16 + col) * 1024;

    float cacc[3][4][4];
    #pragma unroll
    for (int cls = 0; cls < 3; ++cls)
        #pragma unroll
        for (int mi = 0; mi < 4; ++mi)
            #pragma unroll
            for (int r = 0; r < 4; ++r) cacc[cls][mi][r] = 0.f;

    for (int bnp = 0; bnp < 5; ++bnp) {
        const int nblk0 = bnp*16 + wv*4;
        float bias[4], w20[4], w21[4], w22[4];
        #pragma unroll
        for (int ni = 0; ni < 4; ++ni) {
            const int n = (nblk0 + ni)*16 + col;
            const bool vok = n < F_REAL;
            bias[ni] = vok ? b1[n] : 0.f;
            w20[ni]  = vok ? w2[n] : 0.f;
            w21[ni]  = vok ? w2[F_REAL + n] : 0.f;
            w22[ni]  = vok ? w2[2*F_REAL + n] : 0.f;
        }
        f32x4 acc[4][4];
        #pragma unroll
        for (int i = 0; i < 4; ++i)
            #pragma unroll
            for (int j = 0; j < 4; ++j)
                acc[i][j] = (f32x4){0.f, 0.f, 0.f, 0.f};

        uint4 avA[4], bvA[4], avB[4], bvB[4], avC[4], bvC[4];

#define LOADF(AV, BV, kt, TAIL)                                               \
    do {                                                                      \
        if (TAIL) {                                                           \
            _Pragma("unroll")                                                 \
            for (int i = 0; i < 4; ++i)                                       \
                AV[i] = *(const uint4*)(Ascal +                               \
                         (size_t)(bm*64 + i*16 + col)*32 + quad*8);           \
        } else {                                                              \
            _Pragma("unroll")                                                 \
            for (int i = 0; i < 4; ++i)                                       \
                AV[i] = *(const uint4*)(panel + arow[i] +                     \
                         ((((kt)*4 + quad) ^ xmask) * 8));                    \
        }                                                                     \
        _Pragma("unroll")                                                     \
        for (int j = 0; j < 4; ++j)                                           \
            BV[j] = *(const uint4*)(Bm2 +                                     \
                     ((size_t)((kt)*NBLK + nblk0 + j)*64 + lane)*8);          \
    } while (0)

#define COMPUTE(AV, BV, TAIL)                                                 \
    do {                                                                      \
        bf16x8 a[4], b[4];                                                    \
        _Pragma("unroll")                                                     \
        for (int i = 0; i < 4; ++i) {                                         \
            a[i] = __builtin_bit_cast(bf16x8, AV[i]);                         \
            if (TAIL) { if (quad == 0)                                        \
                a[i][7] = __builtin_bit_cast(__bf16, rfb[i]); }               \
        }                                                                     \
        _Pragma("unroll")                                                     \
        for (int j = 0; j < 4; ++j)                                           \
            b[j] = __builtin_bit_cast(bf16x8, BV[j]);                         \
        _Pragma("unroll")                                                     \
        for (int i = 0; i < 4; ++i)                                           \
            _Pragma("unroll")                                                 \
            for (int j = 0; j < 4; ++j)                                       \
                acc[i][j] = __builtin_amdgcn_mfma_f32_16x16x32_bf16(          \
                                a[i], b[j], acc[i][j], 0, 0, 0);              \
    } while (0)

        // depth-2 register pipeline over 33 K-tiles; no barriers needed
        LOADF(avA, bvA, 0, 0);
        LOADF(avB, bvB, 1, 0);
        for (int it = 0; it < 10; ++it) {
            const int k0 = it * 3;
            LOADF(avC, bvC, k0+2, 0);  COMPUTE(avA, bvA, 0);
            LOADF(avA, bvA, k0+3, 0);  COMPUTE(avB, bvB, 0);
            LOADF(avB, bvB, k0+4, 0);  COMPUTE(avC, bvC, 0);
        }
        LOADF(avC, bvC, 32, 1);  COMPUTE(avA, bvA, 0);   // kt 30
        COMPUTE(avB, bvB, 0);                            // kt 31
        COMPUTE(avC, bvC, 1);                            // kt 32 (tail)

        // epilogue accumulation for this 256-col pass
        #pragma unroll
        for (int mi = 0; mi < 4; ++mi)
            #pragma unroll
            for (int ni = 0; ni < 4; ++ni)
                #pragma unroll
                for (int r = 0; r < 4; ++r) {
                    float hd = fmaxf(acc[mi][ni][r] + bias[ni], 0.f);
                    cacc[0][mi][r] += hd * w20[ni];
                    cacc[1][mi][r] += hd * w21[ni];
                    cacc[2][mi][r] += hd * w22[ni];
                }
#undef LOADF
#undef COMPUTE
    }

    // lane-reduce over the 16 cols of each group
    #pragma unroll
    for (int cls = 0; cls < 3; ++cls)
        #pragma unroll
        for (int mi = 0; mi < 4; ++mi)
            #pragma unroll
            for (int r = 0; r < 4; ++r) {
                float v = cacc[cls][mi][r];
                v += __shfl_xor(v, 8, 64);
                v += __shfl_xor(v, 4, 64);
                v += __shfl_xor(v, 2, 64);
                v += __shfl_xor(v, 1, 64);
                cacc[cls][mi][r] = v;
            }

    if (col == 0) {
        #pragma unroll
        for (int cls = 0; cls < 3; ++cls)
            #pragma unroll
            for (int mi = 0; mi < 4; ++mi)
                #pragma unroll
                for (int r = 0; r < 4; ++r)
                    comb[wv*192 + (mi*16 + quad*4 + r)*3 + cls] = cacc[cls][mi][r];
    }
    __syncthreads();
    if (tid < 192) {
        float s = comb[tid] + comb[192+tid] + comb[384+tid] + comb[576+tid]
                + b2[tid % 3];
        out[(size_t)bm * 192 + tid] = s;
    }
}

extern "C" void kernel_launch(void* const* d_in, const int* in_sizes, int n_in,
                              void* d_out, int out_size, void* d_ws, size_t ws_size,
                              hipStream_t stream)
{
    const float* h  = (const float*)d_in[0];
    const float* vp = (const float*)d_in[1];
    const float* vh = (const float*)d_in[2];
    const float* nd = (const float*)d_in[3];
    const float* ns = (const float*)d_in[4];
    const float* w1 = (const float*)d_in[5];
    const float* b1 = (const float*)d_in[6];
    const float* w2 = (const float*)d_in[7];
    const float* b2 = (const float*)d_in[8];
    float* out = (float*)d_out;

    u16* Ascal = (u16*)d_ws;                          // [16384][32] bf16
    u16* Bm2   = Ascal + (size_t)B_ROWS * 32;         // [33][80][4][16][8] bf16

    static bool attr_done = false;
    if (!attr_done) {
        (void)hipFuncSetAttribute((const void*)gemm_kernel,
                                  hipFuncAttributeMaxDynamicSharedMemorySize,
                                  LDS_TOTAL);
        attr_done = true;
    }

    prep_kernel<<<1024, 256, 0, stream>>>(vp, vh, nd, ns, Ascal);
    convw_kernel<<<660, 256, 0, stream>>>(w1, Bm2);
    gemm_kernel<<<256, 256, LDS_TOTAL, stream>>>(h, Ascal, Bm2, b1, w2, b2, out);
}